// Round 12
// baseline (270.082 us; speedup 1.0000x reference)
//
#include <hip/hip_runtime.h>
#include <cfloat>

// Problem constants
#define B_   16
#define C_   256
#define HW_  4096      // 64*64
#define N_   65536     // B_*HW_
#define K_   1024

// Output layout (float32, concatenated flat in return order):
//  [0] loss | [1,+16777216) quantized (b c h w) | [16777217] perplexity
//  [16777218,+67108864) encodings (N,K)
#define OUT_QOFF   1
#define OUT_POFF   16777217
#define OUT_EOFF   16777218

typedef __bf16 bf16x8 __attribute__((ext_vector_type(8)));
typedef float  f32x4  __attribute__((ext_vector_type(4)));
typedef float  f32x16 __attribute__((ext_vector_type(16)));

// ---------------------------------------------------------------- bf16 split
__device__ inline ushort f2bf(float f) {
    union { float f; unsigned u; } a; a.f = f;
    unsigned u = a.u;
    unsigned r = (u + 0x7fffu + ((u >> 16) & 1u)) >> 16;   // RNE
    return (ushort)r;
}
__device__ inline float bf2f(ushort u) {
    union { float f; unsigned u; } a; a.u = ((unsigned)u) << 16; return a.f;
}

// ------------------------------------- prep: pack e (2-split) + enorm + cnt0
// 32x32x16-fragment pack (verified R10): flat step s = ct*16+ks (ct: 32-code
// tile, ks: 16-ch step). Per s: 2048 B = [split(2)][lane(64)][16B] where
// lane = (kin>>3)*32 + (k&31), i = kin&7  (B: col=lane&31, k=(lane>>5)*8+i).
__global__ __launch_bounds__(256) void k_prep(const float* __restrict__ emb,
                                              char* __restrict__ epk,
                                              float* __restrict__ enorm,
                                              int* __restrict__ counts) {
    const int k = blockIdx.x;
    const int c = threadIdx.x;
    float v = emb[k * C_ + c];
    ushort h = f2bf(v);
    ushort m = f2bf(v - bf2f(h));
    int ct = k >> 5, cl = k & 31;
    int ks = c >> 4, kin = c & 15;
    int hf = kin >> 3, i = kin & 7;
    int lane = hf * 32 + cl;
    size_t off = (size_t)(ct * 16 + ks) * 2048 + (size_t)(lane * 16 + i * 2);
    *(ushort*)(epk + off)        = h;
    *(ushort*)(epk + off + 1024) = m;
    float sq = v * v;
    __shared__ float red[4];
#pragma unroll
    for (int o = 32; o > 0; o >>= 1) sq += __shfl_down(sq, o);
    if ((c & 63) == 0) red[c >> 6] = sq;
    __syncthreads();
    if (c == 0) {
        enorm[k]  = (red[0] + red[1]) + (red[2] + red[3]);
        counts[k] = 0;
    }
}

// ---------------------------- 32x32 MFMA argmin, LDS double-buffered B
// Block: 4 waves x 32 rows = 128 rows, all 1024 codes. A (2 bf16 splits,
// 16 ksteps) in 128 VGPR. Per code-tile ct: stage the 32KB epk slab for ct+1
// via global_load_lds while computing 64 MFMAs (4 products x 16 ks) on ct.
// Counted vmcnt(8); 2 barriers per ct (64 MFMA/wave between drains).
// 4-product fp32 emulation: ah*Bh + am*Bh + ah*Bm + am*Bm (R6/R10 numerics).
__global__ __launch_bounds__(256, 2) void k_argmin_mfma(const float* __restrict__ x,
                                                        const char* __restrict__ epk,
                                                        const float* __restrict__ enorm,
                                                        int* __restrict__ bestIdx,
                                                        int* __restrict__ counts) {
    __shared__ __align__(16) char Bs[2][32768];
    __shared__ float En[K_];

    const int tid  = threadIdx.x;
    const int lane = tid & 63;
    const int wid  = tid >> 6;
    const int c0   = lane & 31;          // col-in-tile / row-in-frag
    const int hf   = lane >> 5;          // k-half
    const int row0 = blockIdx.x * 128 + wid * 32;
    const int cpOff = tid * 16;          // 256 thr x 16B x 8 = 32KB slab

    for (int i = tid; i < K_; i += 256) En[i] = enorm[i];

    // ---- A fragments (verified R10): row = row0 + c0, k = ks*16 + hf*8 + i
    union FU { bf16x8 v; ushort u[8]; };
    FU Ah[16], Am[16];
    {
        const int n = row0 + c0;
        const int b = n >> 12, hw = n & 4095;
        const float* xb = x + (size_t)b * (C_ * HW_) + hw;
#pragma unroll
        for (int ks = 0; ks < 16; ++ks) {
#pragma unroll
            for (int i = 0; i < 8; ++i) {
                float v = xb[(size_t)(ks * 16 + hf * 8 + i) * HW_];
                ushort h = f2bf(v);
                Ah[ks].u[i] = h;
                Am[ks].u[i] = f2bf(v - bf2f(h));
            }
        }
    }
    __syncthreads();   // drains vmcnt+lgkmcnt: clean slate for counted vmcnt

// stage code-tile ct_'s 32KB slab into Bs[ct_&1] (8 x 16B per thread;
// src and dst share offset cpOff + j*4096 -- G21 both-sides-or-neither)
#define STAGE(ct_) do {                                                             \
    const char* src_ = epk + (size_t)(ct_) * 32768 + cpOff;                         \
    char* dst_ = &Bs[(ct_) & 1][0] + cpOff;                                         \
    _Pragma("unroll")                                                               \
    for (int j = 0; j < 8; ++j) {                                                   \
        __builtin_amdgcn_global_load_lds(                                           \
            (const __attribute__((address_space(1))) void*)(src_ + j * 4096),       \
            (__attribute__((address_space(3))) void*)(dst_ + j * 4096), 16, 0, 0);  \
    }                                                                               \
} while (0)

    STAGE(0);

    float best[16]; int bidx[16];
#pragma unroll
    for (int t = 0; t < 16; ++t) { best[t] = FLT_MAX; bidx[t] = 0; }
    const f32x16 zero16 = {0,0,0,0,0,0,0,0,0,0,0,0,0,0,0,0};

    for (int ct = 0; ct < 32; ++ct) {
        if (ct < 31) {
            STAGE(ct + 1);
            asm volatile("s_waitcnt vmcnt(8)" ::: "memory");   // ct's slab done
        } else {
            asm volatile("s_waitcnt vmcnt(0)" ::: "memory");
        }
        __builtin_amdgcn_s_barrier();
        asm volatile("" ::: "memory");

        const char* buf = &Bs[ct & 1][0] + lane * 16;
        f32x16 acc1 = zero16, acc2 = zero16;
        __builtin_amdgcn_s_setprio(1);
#pragma unroll
        for (int ks = 0; ks < 16; ++ks) {
            bf16x8 bh = *(const bf16x8*)(buf + ks * 2048);
            bf16x8 bm = *(const bf16x8*)(buf + ks * 2048 + 1024);
            acc1 = __builtin_amdgcn_mfma_f32_32x32x16_bf16(Ah[ks].v, bh, acc1, 0,0,0);
            acc2 = __builtin_amdgcn_mfma_f32_32x32x16_bf16(Am[ks].v, bh, acc2, 0,0,0);
            acc1 = __builtin_amdgcn_mfma_f32_32x32x16_bf16(Ah[ks].v, bm, acc1, 0,0,0);
            acc2 = __builtin_amdgcn_mfma_f32_32x32x16_bf16(Am[ks].v, bm, acc2, 0,0,0);
        }
        __builtin_amdgcn_s_setprio(0);

        // fold (verified R10): lane's col = ct*32+c0 for all 16 regs;
        // row = (t&3) + 8*(t>>2) + 4*hf. Ascending ct + strict < => first-occ.
        const int col = ct * 32 + c0;
        const float en = En[col];
#pragma unroll
        for (int t = 0; t < 16; ++t) {
            float d = fmaf(-2.0f, acc1[t] + acc2[t], en);
            if (d < best[t]) { best[t] = d; bidx[t] = col; }
        }

        asm volatile("s_waitcnt lgkmcnt(0)" ::: "memory");   // buf reads done
        __builtin_amdgcn_s_barrier();                        // before restage
    }
#undef STAGE

    // cross-lane argmin over the 32 cols (lanes sharing hf half)
#pragma unroll
    for (int t = 0; t < 16; ++t) {
        float v  = best[t];
        int   id = bidx[t];
#pragma unroll
        for (int m = 1; m < 32; m <<= 1) {
            float ov = __shfl_xor(v, m);
            int   oi = __shfl_xor(id, m);
            if (ov < v || (ov == v && oi < id)) { v = ov; id = oi; }
        }
        if (c0 == 0) {
            int nn = row0 + (t & 3) + 8 * (t >> 2) + 4 * hf;
            bestIdx[nn] = id;
            atomicAdd(&counts[id], 1);
        }
    }
}

// --------------------------------------------- gather quantized + loss part
__global__ __launch_bounds__(256) void k_quant(const float* __restrict__ x,
                                               const float* __restrict__ emb,
                                               const int* __restrict__ bestIdx,
                                               float* __restrict__ outq,
                                               float* __restrict__ partials) {
    const int tid = threadIdx.x;
    float lsum = 0.f;
#pragma unroll
    for (int it = 0; it < 4; ++it) {
        int q  = blockIdx.x * 256 + tid + it * (4096 * 256);
        int f  = q << 2;
        int hw = f & 4095;
        int c  = (f >> 12) & 255;
        int b  = f >> 20;
        int n0 = (b << 12) + hw;
        int4  id = *(const int4*)&bestIdx[n0];
        float4 xv = *(const float4*)&x[f];
        float q0 = emb[id.x * C_ + c];
        float q1 = emb[id.y * C_ + c];
        float q2 = emb[id.z * C_ + c];
        float q3 = emb[id.w * C_ + c];
        f32x4 ov;
        ov.x = xv.x + (q0 - xv.x);
        ov.y = xv.y + (q1 - xv.y);
        ov.z = xv.z + (q2 - xv.z);
        ov.w = xv.w + (q3 - xv.w);
        __builtin_nontemporal_store(ov, (f32x4*)&outq[f]);
        float d0 = q0 - xv.x, d1 = q1 - xv.y, d2 = q2 - xv.z, d3 = q3 - xv.w;
        lsum += d0 * d0 + d1 * d1 + d2 * d2 + d3 * d3;
    }
    __shared__ float red[4];
#pragma unroll
    for (int o = 32; o > 0; o >>= 1) lsum += __shfl_down(lsum, o);
    if ((tid & 63) == 0) red[tid >> 6] = lsum;
    __syncthreads();
    if (tid == 0) partials[blockIdx.x] = (red[0] + red[1]) + (red[2] + red[3]);
}

// ------------------------------------------------------- one-hot encodings
__global__ __launch_bounds__(256) void k_enc(const int* __restrict__ bestIdx,
                                             float* __restrict__ enc) {
    const int k4 = threadIdx.x * 4;
    int row = blockIdx.x * 8;
#pragma unroll
    for (int j = 0; j < 8; ++j, ++row) {
        int idv = bestIdx[row];
        f32x4 v;
        v.x = (k4 + 0 == idv) ? 1.0f : 0.0f;
        v.y = (k4 + 1 == idv) ? 1.0f : 0.0f;
        v.z = (k4 + 2 == idv) ? 1.0f : 0.0f;
        v.w = (k4 + 3 == idv) ? 1.0f : 0.0f;
        __builtin_nontemporal_store(v, (f32x4*)&enc[(size_t)row * K_ + k4]);
    }
}

// ----------------------------------------------------------------- finalize
__global__ __launch_bounds__(256) void k_final(const float* __restrict__ partials,
                                               const int* __restrict__ counts,
                                               float* __restrict__ out) {
    const int tid = threadIdx.x;
    float s = 0.f;
    for (int i = tid; i < 4096; i += 256) s += partials[i];
    float h = 0.f;
    for (int k = tid; k < K_; k += 256) {
        float p = (float)counts[k] * (1.0f / 65536.0f);
        h += p * logf(p + 1e-10f);
    }
    __shared__ float redS[4], redH[4];
#pragma unroll
    for (int o = 32; o > 0; o >>= 1) {
        s += __shfl_down(s, o);
        h += __shfl_down(h, o);
    }
    if ((tid & 63) == 0) { redS[tid >> 6] = s; redH[tid >> 6] = h; }
    __syncthreads();
    if (tid == 0) {
        float S = (redS[0] + redS[1]) + (redS[2] + redS[3]);
        float H = (redH[0] + redH[1]) + (redH[2] + redH[3]);
        out[0]        = 0.25f * S / 16777216.0f;
        out[OUT_POFF] = expf(-H);
    }
}

extern "C" void kernel_launch(void* const* d_in, const int* in_sizes, int n_in,
                              void* d_out, int out_size, void* d_ws, size_t ws_size,
                              hipStream_t stream) {
    const float* x   = (const float*)d_in[0];
    const float* emb = (const float*)d_in[1];
    float* out = (float*)d_out;
    char*  ws  = (char*)d_ws;

    // Workspace layout
    int*   bestIdx  = (int*)(ws);                 // 262144 B
    int*   counts   = (int*)(ws + 262144);        //   4096 B
    float* partials = (float*)(ws + 266240);      //  16384 B
    float* enorm    = (float*)(ws + 282624);      //   4096 B
    char*  epk      = ws + 286720;                // 1048576 B packed e-splits (2-way)

    k_prep       <<<K_,       256, 0, stream>>>(emb, epk, enorm, counts);
    k_argmin_mfma<<<N_ / 128, 256, 0, stream>>>(x, epk, enorm, bestIdx, counts);
    k_quant      <<<4096,     256, 0, stream>>>(x, emb, bestIdx, out + OUT_QOFF, partials);
    k_enc        <<<8192,     256, 0, stream>>>(bestIdx, out + OUT_EOFF);
    k_final      <<<1,        256, 0, stream>>>(partials, counts, out);
}

// Round 13
// 211.968 us; speedup vs baseline: 1.2742x; 1.2742x over previous
//
#include <hip/hip_runtime.h>
#include <cfloat>

// Problem constants
#define B_   16
#define C_   256
#define HW_  4096      // 64*64
#define N_   65536     // B_*HW_
#define K_   1024

// Output layout (float32, concatenated flat in return order):
//  [0] loss | [1,+16777216) quantized (b c h w) | [16777217] perplexity
//  [16777218,+67108864) encodings (N,K)
#define OUT_QOFF   1
#define OUT_POFF   16777217
#define OUT_EOFF   16777218

typedef __bf16 bf16x8 __attribute__((ext_vector_type(8)));
typedef float  f32x4  __attribute__((ext_vector_type(4)));

// ---------------------------------------------------------------- bf16 split
__device__ inline ushort f2bf(float f) {
    union { float f; unsigned u; } a; a.f = f;
    unsigned u = a.u;
    unsigned r = (u + 0x7fffu + ((u >> 16) & 1u)) >> 16;   // RNE
    return (ushort)r;
}
__device__ inline float bf2f(ushort u) {
    union { float f; unsigned u; } a; a.u = ((unsigned)u) << 16; return a.f;
}

// ------------------------------------- prep: pack e (2-split) + enorm + cnt0
// One block per code k; thread c handles channel c.
// Packed layout per step s in [0,64): s = (k>>5)*2 + (c>>7); within 16384-B
// block: [split(2)][cg(16)][code(32)][ci(8)] bf16.
__global__ __launch_bounds__(256) void k_prep(const float* __restrict__ emb,
                                              char* __restrict__ epk,
                                              float* __restrict__ enorm,
                                              int* __restrict__ counts) {
    const int k = blockIdx.x;
    const int c = threadIdx.x;
    float v = emb[k * C_ + c];
    ushort h = f2bf(v);
    ushort m = f2bf(v - bf2f(h));
    int s  = (k >> 5) * 2 + (c >> 7);
    int cl = c & 127;
    size_t off = (size_t)s * 16384 + (size_t)((cl >> 3) * 512 + (k & 31) * 16 + (cl & 7) * 2);
    *(ushort*)(epk + off)        = h;
    *(ushort*)(epk + off + 8192) = m;
    float sq = v * v;
    __shared__ float red[4];
#pragma unroll
    for (int o = 32; o > 0; o >>= 1) sq += __shfl_down(sq, o);
    if ((c & 63) == 0) red[c >> 6] = sq;
    __syncthreads();
    if (c == 0) {
        enorm[k]  = (red[0] + red[1]) + (red[2] + red[3]);
        counts[k] = 0;
    }
}

// -------------------------- MFMA argmin GEMM + fused one-hot encodings write
// Block: 64 rows x 1024 codes, 4 waves (16 rows each). A (2 bf16 splits) in
// 64 VGPR; B (2 splits) double-buffered in LDS. 37.1 KB LDS + <=128 VGPR
// (launch_bounds(256,4)) -> 4 blocks/CU. Epilogue writes this wave's 16
// one-hot rows (256 MB total) NT -- hidden under argmin's idle HBM pipe.
// 4-product fp32 emulation: ah*Bh + am*Bh + ah*Bm + am*Bm (R6/R11 numerics).
__global__ __launch_bounds__(256, 4) void k_argmin_mfma(const float* __restrict__ x,
                                                        const char* __restrict__ epk,
                                                        const float* __restrict__ enorm,
                                                        int* __restrict__ bestIdx,
                                                        int* __restrict__ counts,
                                                        float* __restrict__ enc) {
    __shared__ __align__(16) char Bs[2][16384];
    __shared__ float En[K_];
    __shared__ int widx[4][16];

    const int tid  = threadIdx.x;
    const int lane = tid & 63;
    const int wid  = tid >> 6;
    const int l15  = lane & 15;
    const int kg   = lane >> 4;
    const int row0 = blockIdx.x * 64;
    const int cpOff = wid * 1024 + lane * 16;   // wave's copy offset (4KB/wave)

    for (int i = tid; i < K_; i += 256) En[i] = enorm[i];

    // ---- A fragments: row = row0 + wid*16 + l15, k-elems = kg*8+i
    union FU { bf16x8 v; ushort u[8]; };
    FU Ah[8], Am[8];
    {
        const int n  = row0 + wid * 16 + l15;
        const int b  = n >> 12, hw = n & 4095;
        const float* xb = x + (size_t)b * (C_ * HW_) + hw;
#pragma unroll
        for (int cb = 0; cb < 8; ++cb) {
#pragma unroll
            for (int i = 0; i < 8; ++i) {
                float v = xb[(cb * 32 + kg * 8 + i) * HW_];
                ushort h = f2bf(v);
                Ah[cb].u[i] = h;
                Am[cb].u[i] = f2bf(v - bf2f(h));
            }
        }
    }
    __syncthreads();   // drains vmcnt+lgkmcnt: clean slate for counting

    // ---- stage step 0 (src and dst share the same offset: cpOff+j*4096)
    {
        const char* src = epk + (size_t)cpOff;
        char* dstb = &Bs[0][0] + cpOff;
#pragma unroll
        for (int j = 0; j < 4; ++j) {
            __builtin_amdgcn_global_load_lds(
                (const __attribute__((address_space(1))) void*)(src + j * 4096),
                (__attribute__((address_space(3))) void*)(dstb + j * 4096), 16, 0, 0);
        }
    }

    float best[4] = {FLT_MAX, FLT_MAX, FLT_MAX, FLT_MAX};
    int   bidx[4] = {0, 0, 0, 0};
    const int laneB = kg * 512 + l15 * 16;
    const f32x4 zero = {0.f, 0.f, 0.f, 0.f};
    f32x4 accA, accB;

#define STEP(H, IS_LAST) do {                                                       \
    if (!(IS_LAST)) {                                                               \
        int sn = 2 * kt + (H) + 1;                                                  \
        const char* src = epk + (size_t)sn * 16384 + (size_t)cpOff;                 \
        char* dstb = &Bs[1 - (H)][0] + cpOff;                                       \
        _Pragma("unroll")                                                           \
        for (int j = 0; j < 4; ++j) {                                               \
            __builtin_amdgcn_global_load_lds(                                       \
                (const __attribute__((address_space(1))) void*)(src + j * 4096),    \
                (__attribute__((address_space(3))) void*)(dstb + j * 4096),         \
                16, 0, 0);                                                          \
        }                                                                           \
        asm volatile("s_waitcnt vmcnt(4)" ::: "memory");                            \
    } else {                                                                        \
        asm volatile("s_waitcnt vmcnt(0)" ::: "memory");                            \
    }                                                                               \
    __builtin_amdgcn_s_barrier();                                                   \
    asm volatile("" ::: "memory");                                                  \
    {                                                                               \
        const char* bbase = &Bs[(H)][0] + laneB;                                    \
        _Pragma("unroll")                                                           \
        for (int cbl = 0; cbl < 4; ++cbl) {                                         \
            const char* bp = bbase + cbl * 2048;                                    \
            bf16x8 Bh0 = *(const bf16x8*)(bp);                                      \
            bf16x8 Bm0 = *(const bf16x8*)(bp + 8192);                               \
            bf16x8 Bh1 = *(const bf16x8*)(bp + 256);                                \
            bf16x8 Bm1 = *(const bf16x8*)(bp + 8448);                               \
            const bf16x8 ah = Ah[(H) * 4 + cbl].v;                                  \
            const bf16x8 am = Am[(H) * 4 + cbl].v;                                  \
            accA = __builtin_amdgcn_mfma_f32_16x16x32_bf16(ah, Bh0, accA, 0,0,0);   \
            accB = __builtin_amdgcn_mfma_f32_16x16x32_bf16(ah, Bh1, accB, 0,0,0);   \
            accA = __builtin_amdgcn_mfma_f32_16x16x32_bf16(am, Bh0, accA, 0,0,0);   \
            accB = __builtin_amdgcn_mfma_f32_16x16x32_bf16(am, Bh1, accB, 0,0,0);   \
            accA = __builtin_amdgcn_mfma_f32_16x16x32_bf16(ah, Bm0, accA, 0,0,0);   \
            accB = __builtin_amdgcn_mfma_f32_16x16x32_bf16(ah, Bm1, accB, 0,0,0);   \
            accA = __builtin_amdgcn_mfma_f32_16x16x32_bf16(am, Bm0, accA, 0,0,0);   \
            accB = __builtin_amdgcn_mfma_f32_16x16x32_bf16(am, Bm1, accB, 0,0,0);   \
        }                                                                           \
    }                                                                               \
    asm volatile("s_waitcnt lgkmcnt(0)" ::: "memory");                              \
    __builtin_amdgcn_s_barrier();                                                   \
} while (0)

    for (int kt = 0; kt < 32; ++kt) {
        accA = zero; accB = zero;
        STEP(0, false);
        STEP(1, kt == 31);
        // fold: lane holds cols cA = kt*32+l15 (tile0), cB = cA+16 (tile1);
        // rows = kg*4 + r. Ascending k + strict < => first-occurrence.
        const int cA = kt * 32 + l15;
        const int cB = cA + 16;
        const float enA = En[cA], enB = En[cB];
#pragma unroll
        for (int r = 0; r < 4; ++r) {
            float dA = enA - 2.0f * accA[r];
            if (dA < best[r]) { best[r] = dA; bidx[r] = cA; }
            float dB = enB - 2.0f * accB[r];
            if (dB < best[r]) { best[r] = dB; bidx[r] = cB; }
        }
    }
#undef STEP

    // cross-lane argmin over the 16 cols (lanes sharing kg group)
#pragma unroll
    for (int r = 0; r < 4; ++r) {
        float v  = best[r];
        int   id = bidx[r];
#pragma unroll
        for (int m = 1; m < 16; m <<= 1) {
            float ov = __shfl_xor(v, m);
            int   oi = __shfl_xor(id, m);
            if (ov < v || (ov == v && oi < id)) { v = ov; id = oi; }
        }
        if (l15 == 0) {
            int n = row0 + wid * 16 + kg * 4 + r;
            bestIdx[n] = id;
            atomicAdd(&counts[id], 1);
            widx[wid][kg * 4 + r] = id;     // wave-local broadcast via LDS
        }
    }
    asm volatile("s_waitcnt lgkmcnt(0)" ::: "memory");   // widx visible in-wave

    // ---- fused one-hot write: this wave's 16 rows, NT coalesced stores.
    // Row rr -> enc[(row0+wid*16+rr)*K]; lane covers k = c*256 + lane*4 + j.
    {
        float* encp = enc + (size_t)(row0 + wid * 16) * K_ + lane * 4;
#pragma unroll
        for (int rr = 0; rr < 16; ++rr) {
            const int idv = widx[wid][rr];
            float* rp = encp + (size_t)rr * K_;
#pragma unroll
            for (int c = 0; c < 4; ++c) {
                const int k0 = c * 256 + lane * 4;
                f32x4 v;
                v.x = (k0 + 0 == idv) ? 1.0f : 0.0f;
                v.y = (k0 + 1 == idv) ? 1.0f : 0.0f;
                v.z = (k0 + 2 == idv) ? 1.0f : 0.0f;
                v.w = (k0 + 3 == idv) ? 1.0f : 0.0f;
                __builtin_nontemporal_store(v, (f32x4*)(rp + c * 256));
            }
        }
    }
}

// --------------------------------------------- gather quantized + loss part
__global__ __launch_bounds__(256) void k_quant(const float* __restrict__ x,
                                               const float* __restrict__ emb,
                                               const int* __restrict__ bestIdx,
                                               float* __restrict__ outq,
                                               float* __restrict__ partials) {
    const int tid = threadIdx.x;
    float lsum = 0.f;
#pragma unroll
    for (int it = 0; it < 4; ++it) {
        int q  = blockIdx.x * 256 + tid + it * (4096 * 256);
        int f  = q << 2;
        int hw = f & 4095;
        int c  = (f >> 12) & 255;
        int b  = f >> 20;
        int n0 = (b << 12) + hw;
        int4  id = *(const int4*)&bestIdx[n0];
        float4 xv = *(const float4*)&x[f];
        float q0 = emb[id.x * C_ + c];
        float q1 = emb[id.y * C_ + c];
        float q2 = emb[id.z * C_ + c];
        float q3 = emb[id.w * C_ + c];
        f32x4 ov;
        ov.x = xv.x + (q0 - xv.x);
        ov.y = xv.y + (q1 - xv.y);
        ov.z = xv.z + (q2 - xv.z);
        ov.w = xv.w + (q3 - xv.w);
        __builtin_nontemporal_store(ov, (f32x4*)&outq[f]);
        float d0 = q0 - xv.x, d1 = q1 - xv.y, d2 = q2 - xv.z, d3 = q3 - xv.w;
        lsum += d0 * d0 + d1 * d1 + d2 * d2 + d3 * d3;
    }
    __shared__ float red[4];
#pragma unroll
    for (int o = 32; o > 0; o >>= 1) lsum += __shfl_down(lsum, o);
    if ((tid & 63) == 0) red[tid >> 6] = lsum;
    __syncthreads();
    if (tid == 0) partials[blockIdx.x] = (red[0] + red[1]) + (red[2] + red[3]);
}

// ----------------------------------------------------------------- finalize
__global__ __launch_bounds__(256) void k_final(const float* __restrict__ partials,
                                               const int* __restrict__ counts,
                                               float* __restrict__ out) {
    const int tid = threadIdx.x;
    float s = 0.f;
    for (int i = tid; i < 4096; i += 256) s += partials[i];
    float h = 0.f;
    for (int k = tid; k < K_; k += 256) {
        float p = (float)counts[k] * (1.0f / 65536.0f);
        h += p * logf(p + 1e-10f);
    }
    __shared__ float redS[4], redH[4];
#pragma unroll
    for (int o = 32; o > 0; o >>= 1) {
        s += __shfl_down(s, o);
        h += __shfl_down(h, o);
    }
    if ((tid & 63) == 0) { redS[tid >> 6] = s; redH[tid >> 6] = h; }
    __syncthreads();
    if (tid == 0) {
        float S = (redS[0] + redS[1]) + (redS[2] + redS[3]);
        float H = (redH[0] + redH[1]) + (redH[2] + redH[3]);
        out[0]        = 0.25f * S / 16777216.0f;
        out[OUT_POFF] = expf(-H);
    }
}

extern "C" void kernel_launch(void* const* d_in, const int* in_sizes, int n_in,
                              void* d_out, int out_size, void* d_ws, size_t ws_size,
                              hipStream_t stream) {
    const float* x   = (const float*)d_in[0];
    const float* emb = (const float*)d_in[1];
    float* out = (float*)d_out;
    char*  ws  = (char*)d_ws;

    // Workspace layout
    int*   bestIdx  = (int*)(ws);                 // 262144 B
    int*   counts   = (int*)(ws + 262144);        //   4096 B
    float* partials = (float*)(ws + 266240);      //  16384 B
    float* enorm    = (float*)(ws + 282624);      //   4096 B
    char*  epk      = ws + 286720;                // 1048576 B packed e-splits (2-way)

    k_prep       <<<K_,      256, 0, stream>>>(emb, epk, enorm, counts);
    k_argmin_mfma<<<N_ / 64, 256, 0, stream>>>(x, epk, enorm, bestIdx, counts,
                                               out + OUT_EOFF);
    k_quant      <<<4096,    256, 0, stream>>>(x, emb, bestIdx, out + OUT_QOFF, partials);
    k_final      <<<1,       256, 0, stream>>>(partials, counts, out);
}

// Round 14
// 210.346 us; speedup vs baseline: 1.2840x; 1.0077x over previous
//
#include <hip/hip_runtime.h>
#include <cfloat>

// Problem constants
#define B_   16
#define C_   256
#define HW_  4096      // 64*64
#define N_   65536     // B_*HW_
#define K_   1024

// Output layout (float32, concatenated flat in return order):
//  [0] loss | [1,+16777216) quantized (b c h w) | [16777217] perplexity
//  [16777218,+67108864) encodings (N,K)
#define OUT_QOFF   1
#define OUT_POFF   16777217
#define OUT_EOFF   16777218

typedef __bf16 bf16x8 __attribute__((ext_vector_type(8)));
typedef float  f32x4  __attribute__((ext_vector_type(4)));

// ---------------------------------------------------------------- bf16 split
__device__ inline ushort f2bf(float f) {
    union { float f; unsigned u; } a; a.f = f;
    unsigned u = a.u;
    unsigned r = (u + 0x7fffu + ((u >> 16) & 1u)) >> 16;   // RNE
    return (ushort)r;
}
__device__ inline float bf2f(ushort u) {
    union { float f; unsigned u; } a; a.u = ((unsigned)u) << 16; return a.f;
}

// ------------------------------------- prep: pack e (2-split) + enorm + cnt0
// One block per code k; thread c handles channel c.
// Packed layout per step s in [0,64): s = (k>>5)*2 + (c>>7); within 16384-B
// block: [split(2)][cg(16)][code(32)][ci(8)] bf16.
__global__ __launch_bounds__(256) void k_prep(const float* __restrict__ emb,
                                              char* __restrict__ epk,
                                              float* __restrict__ enorm,
                                              int* __restrict__ counts) {
    const int k = blockIdx.x;
    const int c = threadIdx.x;
    float v = emb[k * C_ + c];
    ushort h = f2bf(v);
    ushort m = f2bf(v - bf2f(h));
    int s  = (k >> 5) * 2 + (c >> 7);
    int cl = c & 127;
    size_t off = (size_t)s * 16384 + (size_t)((cl >> 3) * 512 + (k & 31) * 16 + (cl & 7) * 2);
    *(ushort*)(epk + off)        = h;
    *(ushort*)(epk + off + 8192) = m;
    float sq = v * v;
    __shared__ float red[4];
#pragma unroll
    for (int o = 32; o > 0; o >>= 1) sq += __shfl_down(sq, o);
    if ((c & 63) == 0) red[c >> 6] = sq;
    __syncthreads();
    if (c == 0) {
        enorm[k]  = (red[0] + red[1]) + (red[2] + red[3]);
        counts[k] = 0;
    }
}

// ---------- MFMA argmin GEMM + fused one-hot + quantized + loss epilogue
// Block: 64 rows x 1024 codes, 4 waves (16 rows each). A (2 bf16 splits) in
// 64 VGPR; B (2 splits) double-buffered in LDS. <=128 VGPR (256,4) -> 4
// blocks/CU. Epilogue: enc one-hot rows (NT), quantized = gathered emb row
// (NT, 64B segments), loss = ||x||^2 + best distance (no elementwise pass).
// 4-product fp32 emulation: ah*Bh + am*Bh + ah*Bm + am*Bm (R6/R11 numerics).
__global__ __launch_bounds__(256, 4) void k_argmin_mfma(const float* __restrict__ x,
                                                        const char* __restrict__ epk,
                                                        const float* __restrict__ enorm,
                                                        const float* __restrict__ emb,
                                                        int* __restrict__ bestIdx,
                                                        int* __restrict__ counts,
                                                        float* __restrict__ enc,
                                                        float* __restrict__ outq,
                                                        float* __restrict__ partials) {
    __shared__ __align__(16) char Bs[2][16384];
    __shared__ float En[K_];
    __shared__ int   widx[4][16];
    __shared__ float xn[4][16];

    const int tid  = threadIdx.x;
    const int lane = tid & 63;
    const int wid  = tid >> 6;
    const int l15  = lane & 15;
    const int kg   = lane >> 4;
    const int row0 = blockIdx.x * 64;
    const int cpOff = wid * 1024 + lane * 16;   // wave's copy offset (4KB/wave)

    for (int i = tid; i < K_; i += 256) En[i] = enorm[i];

    // ---- A fragments: row = row0 + wid*16 + l15, k-elems = kg*8+i.
    //      Also accumulate ||x_row||^2 (fp32) and park it in LDS.
    union FU { bf16x8 v; ushort u[8]; };
    FU Ah[8], Am[8];
    {
        const int n  = row0 + wid * 16 + l15;
        const int b  = n >> 12, hw = n & 4095;
        const float* xb = x + (size_t)b * (C_ * HW_) + hw;
        float xs = 0.f;
#pragma unroll
        for (int cb = 0; cb < 8; ++cb) {
#pragma unroll
            for (int i = 0; i < 8; ++i) {
                float v = xb[(cb * 32 + kg * 8 + i) * HW_];
                xs += v * v;
                ushort h = f2bf(v);
                Ah[cb].u[i] = h;
                Am[cb].u[i] = f2bf(v - bf2f(h));
            }
        }
        xs += __shfl_xor(xs, 16);
        xs += __shfl_xor(xs, 32);          // all kg lanes: full row sum
        if (kg == 0) xn[wid][l15] = xs;
    }
    __syncthreads();   // drains vmcnt+lgkmcnt: clean slate for counting

    // ---- stage step 0 (src and dst share the same offset: cpOff+j*4096)
    {
        const char* src = epk + (size_t)cpOff;
        char* dstb = &Bs[0][0] + cpOff;
#pragma unroll
        for (int j = 0; j < 4; ++j) {
            __builtin_amdgcn_global_load_lds(
                (const __attribute__((address_space(1))) void*)(src + j * 4096),
                (__attribute__((address_space(3))) void*)(dstb + j * 4096), 16, 0, 0);
        }
    }

    float best[4] = {FLT_MAX, FLT_MAX, FLT_MAX, FLT_MAX};
    int   bidx[4] = {0, 0, 0, 0};
    const int laneB = kg * 512 + l15 * 16;
    const f32x4 zero = {0.f, 0.f, 0.f, 0.f};
    f32x4 accA, accB;

#define STEP(H, IS_LAST) do {                                                       \
    if (!(IS_LAST)) {                                                               \
        int sn = 2 * kt + (H) + 1;                                                  \
        const char* src = epk + (size_t)sn * 16384 + (size_t)cpOff;                 \
        char* dstb = &Bs[1 - (H)][0] + cpOff;                                       \
        _Pragma("unroll")                                                           \
        for (int j = 0; j < 4; ++j) {                                               \
            __builtin_amdgcn_global_load_lds(                                       \
                (const __attribute__((address_space(1))) void*)(src + j * 4096),    \
                (__attribute__((address_space(3))) void*)(dstb + j * 4096),         \
                16, 0, 0);                                                          \
        }                                                                           \
        asm volatile("s_waitcnt vmcnt(4)" ::: "memory");                            \
    } else {                                                                        \
        asm volatile("s_waitcnt vmcnt(0)" ::: "memory");                            \
    }                                                                               \
    __builtin_amdgcn_s_barrier();                                                   \
    asm volatile("" ::: "memory");                                                  \
    {                                                                               \
        const char* bbase = &Bs[(H)][0] + laneB;                                    \
        _Pragma("unroll")                                                           \
        for (int cbl = 0; cbl < 4; ++cbl) {                                         \
            const char* bp = bbase + cbl * 2048;                                    \
            bf16x8 Bh0 = *(const bf16x8*)(bp);                                      \
            bf16x8 Bm0 = *(const bf16x8*)(bp + 8192);                               \
            bf16x8 Bh1 = *(const bf16x8*)(bp + 256);                                \
            bf16x8 Bm1 = *(const bf16x8*)(bp + 8448);                               \
            const bf16x8 ah = Ah[(H) * 4 + cbl].v;                                  \
            const bf16x8 am = Am[(H) * 4 + cbl].v;                                  \
            accA = __builtin_amdgcn_mfma_f32_16x16x32_bf16(ah, Bh0, accA, 0,0,0);   \
            accB = __builtin_amdgcn_mfma_f32_16x16x32_bf16(ah, Bh1, accB, 0,0,0);   \
            accA = __builtin_amdgcn_mfma_f32_16x16x32_bf16(am, Bh0, accA, 0,0,0);   \
            accB = __builtin_amdgcn_mfma_f32_16x16x32_bf16(am, Bh1, accB, 0,0,0);   \
            accA = __builtin_amdgcn_mfma_f32_16x16x32_bf16(ah, Bm0, accA, 0,0,0);   \
            accB = __builtin_amdgcn_mfma_f32_16x16x32_bf16(ah, Bm1, accB, 0,0,0);   \
            accA = __builtin_amdgcn_mfma_f32_16x16x32_bf16(am, Bm0, accA, 0,0,0);   \
            accB = __builtin_amdgcn_mfma_f32_16x16x32_bf16(am, Bm1, accB, 0,0,0);   \
        }                                                                           \
    }                                                                               \
    asm volatile("s_waitcnt lgkmcnt(0)" ::: "memory");                              \
    __builtin_amdgcn_s_barrier();                                                   \
} while (0)

    for (int kt = 0; kt < 32; ++kt) {
        accA = zero; accB = zero;
        STEP(0, false);
        STEP(1, kt == 31);
        // fold: lane holds cols cA = kt*32+l15 (tile0), cB = cA+16 (tile1);
        // rows = kg*4 + r. Ascending k + strict < => first-occurrence.
        const int cA = kt * 32 + l15;
        const int cB = cA + 16;
        const float enA = En[cA], enB = En[cB];
#pragma unroll
        for (int r = 0; r < 4; ++r) {
            float dA = enA - 2.0f * accA[r];
            if (dA < best[r]) { best[r] = dA; bidx[r] = cA; }
            float dB = enB - 2.0f * accB[r];
            if (dB < best[r]) { best[r] = dB; bidx[r] = cB; }
        }
    }
#undef STEP

    // cross-lane argmin over the 16 cols + loss accumulation
    float wls = 0.f;   // valid at l15==0 lanes
#pragma unroll
    for (int r = 0; r < 4; ++r) {
        float v  = best[r];
        int   id = bidx[r];
#pragma unroll
        for (int m = 1; m < 16; m <<= 1) {
            float ov = __shfl_xor(v, m);
            int   oi = __shfl_xor(id, m);
            if (ov < v || (ov == v && oi < id)) { v = ov; id = oi; }
        }
        if (l15 == 0) {
            int rr = kg * 4 + r;
            int n  = row0 + wid * 16 + rr;
            bestIdx[n] = id;
            atomicAdd(&counts[id], 1);
            widx[wid][rr] = id;             // wave-local broadcast via LDS
            wls += v + xn[wid][rr];         // row loss = ||x||^2 + min dist
        }
    }
    // fold wave loss across the 4 kg-leader lanes (0,16,32,48)
    wls += __shfl_xor(wls, 16);
    wls += __shfl_xor(wls, 32);
    if (lane == 0) partials[blockIdx.x * 4 + wid] = wls;

    asm volatile("s_waitcnt lgkmcnt(0)" ::: "memory");   // widx visible in-wave

    // ---- fused one-hot write: this wave's 16 rows, NT coalesced stores.
    {
        float* encp = enc + (size_t)(row0 + wid * 16) * K_ + lane * 4;
#pragma unroll
        for (int rr = 0; rr < 16; ++rr) {
            const int idv = widx[wid][rr];
            float* rp = encp + (size_t)rr * K_;
#pragma unroll
            for (int c = 0; c < 4; ++c) {
                const int k0 = c * 256 + lane * 4;
                f32x4 v;
                v.x = (k0 + 0 == idv) ? 1.0f : 0.0f;
                v.y = (k0 + 1 == idv) ? 1.0f : 0.0f;
                v.z = (k0 + 2 == idv) ? 1.0f : 0.0f;
                v.w = (k0 + 3 == idv) ? 1.0f : 0.0f;
                __builtin_nontemporal_store(v, (f32x4*)(rp + c * 256));
            }
        }
    }

    // ---- fused quantized write: out[b][c][hw] = emb[widx[r]][c].
    // lane = ci*16 + r: 4 channels x 16 contiguous hw = full 64B segments.
    {
        const int r  = l15;
        const int ci = kg;
        const int n0 = row0 + wid * 16;
        const int b  = n0 >> 12, hw = n0 & 4095;
        const int idv = widx[wid][r];
        const float* ep = emb + (size_t)idv * C_ + ci;
        float* op = outq + (size_t)b * (C_ * HW_) + (size_t)ci * HW_ + hw + r;
#pragma unroll
        for (int cb = 0; cb < 64; ++cb) {
            float qv = ep[cb * 4];
            __builtin_nontemporal_store(qv, op + (size_t)(cb * 4) * HW_);
        }
    }
}

// ----------------------------------------------------------------- finalize
__global__ __launch_bounds__(256) void k_final(const float* __restrict__ partials,
                                               const int* __restrict__ counts,
                                               float* __restrict__ out) {
    const int tid = threadIdx.x;
    float s = 0.f;
    for (int i = tid; i < 4096; i += 256) s += partials[i];
    float h = 0.f;
    for (int k = tid; k < K_; k += 256) {
        float p = (float)counts[k] * (1.0f / 65536.0f);
        h += p * logf(p + 1e-10f);
    }
    __shared__ float redS[4], redH[4];
#pragma unroll
    for (int o = 32; o > 0; o >>= 1) {
        s += __shfl_down(s, o);
        h += __shfl_down(h, o);
    }
    if ((tid & 63) == 0) { redS[tid >> 6] = s; redH[tid >> 6] = h; }
    __syncthreads();
    if (tid == 0) {
        float S = (redS[0] + redS[1]) + (redS[2] + redS[3]);
        float H = (redH[0] + redH[1]) + (redH[2] + redH[3]);
        out[0]        = 0.25f * S / 16777216.0f;
        out[OUT_POFF] = expf(-H);
    }
}

extern "C" void kernel_launch(void* const* d_in, const int* in_sizes, int n_in,
                              void* d_out, int out_size, void* d_ws, size_t ws_size,
                              hipStream_t stream) {
    const float* x   = (const float*)d_in[0];
    const float* emb = (const float*)d_in[1];
    float* out = (float*)d_out;
    char*  ws  = (char*)d_ws;

    // Workspace layout
    int*   bestIdx  = (int*)(ws);                 // 262144 B
    int*   counts   = (int*)(ws + 262144);        //   4096 B
    float* partials = (float*)(ws + 266240);      //  16384 B
    float* enorm    = (float*)(ws + 282624);      //   4096 B
    char*  epk      = ws + 286720;                // 1048576 B packed e-splits (2-way)

    k_prep       <<<K_,      256, 0, stream>>>(emb, epk, enorm, counts);
    k_argmin_mfma<<<N_ / 64, 256, 0, stream>>>(x, epk, enorm, emb, bestIdx, counts,
                                               out + OUT_EOFF, out + OUT_QOFF,
                                               partials);
    k_final      <<<1,       256, 0, stream>>>(partials, counts, out);
}